// Round 8
// baseline (326.046 us; speedup 1.0000x reference)
//
#include <hip/hip_runtime.h>
#include <hip/hip_bf16.h>

#define NN 50000
#define NPAD 50048              // 391 * 128
#define EE 300000
#define ETOT (EE + NN)          // 350000 edges incl self-loops
#define GG 64
#define GCOLS 832               // 64 + 3*256
#define LATD 256
#define BM 128
#define BN 128
#define NB_SCAN 196             // (NN+255)/256
#define LOG2E 1.4426950408889634f

typedef unsigned short u16;
typedef short s16x8 __attribute__((ext_vector_type(8)));
typedef float f32x4 __attribute__((ext_vector_type(4)));

__device__ __forceinline__ u16 f2bf(float f) {
    union { float f; unsigned u; } v; v.f = f;
    unsigned r = v.u + 0x7FFFu + ((v.u >> 16) & 1u);
    return (u16)(r >> 16);
}
__device__ __forceinline__ float bf2f(u16 u) {
    union { unsigned u; float f; } v; v.u = ((unsigned)u) << 16;
    return v.f;
}

// ---------------- prep: weight transposes | n0+pool | edge count | pad zero ----------------
__global__ __launch_bounds__(256) void k_prep(const float* __restrict__ W1, const float* __restrict__ W2,
                                              const float* __restrict__ W3, u16* __restrict__ Wt1,
                                              u16* __restrict__ Wt2, u16* __restrict__ Wt3,
                                              const float* __restrict__ bf, const float* __restrict__ Wb,
                                              const float* __restrict__ bb, const int* __restrict__ batch,
                                              u16* __restrict__ n0bf, int* __restrict__ gbuf,
                                              const int* __restrict__ ei, int* __restrict__ counts,
                                              u16* __restrict__ nbf) {
    int b = blockIdx.x;
    if (b < 576) {
        int idx = b * 256 + threadIdx.x;
        if (idx < 16384) {
            int n = idx >> 6, k = idx & 63;
            Wt1[idx] = f2bf(W1[k * 256 + n]);
        } else if (idx < 81920) {
            int t = idx - 16384; int n = t >> 8, k = t & 255;
            Wt2[t] = f2bf(W2[k * 256 + n]);
        } else {
            int t = idx - 81920; int n = t >> 8, k = t & 255;
            Wt3[t] = f2bf(W3[k * 256 + n]);
        }
    } else if (b < 967) {
        int c = threadIdx.x & 63;
        int sub = threadIdx.x >> 6;
        int base = (b - 576) * 128;
        int end = min(base + 128, NN);
        float w0 = Wb[c], w1 = Wb[64 + c], w2 = Wb[128 + c], w3 = Wb[192 + c], w4 = Wb[256 + c], bb_ = bb[c];
        float mx = 0.f;
        int curg = -1;
        for (int n = base + sub; n < end; n += 4) {
            const float* r = bf + (size_t)n * 5;
            float v = bb_ + r[0] * w0 + r[1] * w1 + r[2] * w2 + r[3] * w3 + r[4] * w4;
            v = fmaxf(v, 0.f);
            n0bf[(size_t)n * 64 + c] = f2bf(v);
            int g = batch[n];
            if (g != curg) {
                if (curg >= 0) atomicMax(&gbuf[curg * GCOLS + c], __float_as_int(mx));
                mx = 0.f; curg = g;
            }
            mx = fmaxf(mx, v);
        }
        if (curg >= 0) atomicMax(&gbuf[curg * GCOLS + c], __float_as_int(mx));
    } else if (b < 2335) {
        int e = (b - 967) * 256 + threadIdx.x;
        if (e < ETOT) {
            int d = (e < EE) ? ei[EE + e] : (e - EE);
            atomicAdd(&counts[d], 1);
        }
    } else {
        u16* p0 = n0bf + (size_t)NN * 64;
        for (int i = threadIdx.x; i < (NPAD - NN) * 64; i += 256) p0[i] = 0;
        u16* p1 = nbf + (size_t)NN * 256;
        for (int i = threadIdx.x; i < (NPAD - NN) * 256; i += 256) p1[i] = 0;
    }
}

// ---------------- CSR scan ----------------
__global__ __launch_bounds__(256) void k_scan_block(const int* __restrict__ counts, int* __restrict__ scanned,
                                                    int* __restrict__ bsums, int n) {
    __shared__ int sh[256];
    int i = blockIdx.x * 256 + threadIdx.x;
    int v = (i < n) ? counts[i] : 0;
    sh[threadIdx.x] = v; __syncthreads();
    for (int d = 1; d < 256; d <<= 1) {
        int t = (threadIdx.x >= d) ? sh[threadIdx.x - d] : 0;
        __syncthreads();
        sh[threadIdx.x] += t;
        __syncthreads();
    }
    if (i < n) scanned[i] = sh[threadIdx.x] - v;
    if (threadIdx.x == 255) bsums[blockIdx.x] = sh[255];
}

__global__ __launch_bounds__(256) void k_scan_add2(const int* __restrict__ scanned, const int* __restrict__ bsums,
                                                   int* __restrict__ indptr, int* __restrict__ fill) {
    __shared__ int sh[256];
    int t = threadIdx.x;
    int v = (t < NB_SCAN) ? bsums[t] : 0;
    sh[t] = v; __syncthreads();
    for (int d = 1; d < 256; d <<= 1) {
        int u = (t >= d) ? sh[t - d] : 0;
        __syncthreads();
        sh[t] += u;
        __syncthreads();
    }
    int bix = blockIdx.x;
    int boff = (bix == 0) ? 0 : sh[bix - 1];
    int i = bix * 256 + t;
    if (i < NN) { indptr[i] = scanned[i] + boff; fill[i] = 0; }
    if (i == 0) indptr[NN] = ETOT;
}

__global__ __launch_bounds__(256) void k_fill(const int* __restrict__ ei, const int* __restrict__ indptr,
                                              int* __restrict__ fill, int* __restrict__ esrc) {
    int e = blockIdx.x * 256 + threadIdx.x;
    if (e >= ETOT) return;
    int s, d;
    if (e < EE) { s = ei[e]; d = ei[EE + e]; } else { s = d = e - EE; }
    int pos = atomicAdd(&fill[d], 1);
    esrc[indptr[d] + pos] = s;
}

// ---------------- bf16 MFMA GEMM + fused a_s/a_d epilogue (scores pre-scaled by log2e) ----------------
__global__ __launch_bounds__(256) void k_gemm_mfma(const u16* __restrict__ A,
                                                   const u16* __restrict__ Bt,
                                                   const float* __restrict__ att_s,
                                                   const float* __restrict__ att_d,
                                                   u16* __restrict__ Hbf,
                                                   float* __restrict__ a_s,
                                                   float* __restrict__ a_d,
                                                   int K) {
    __shared__ __align__(16) u16 As[128 * 64];
    __shared__ __align__(16) u16 Bs[128 * 64];
    const int tid = threadIdx.x;
    const int lane = tid & 63;
    const int w = tid >> 6;
    const int wr = w >> 1, wc = w & 1;
    const int row0 = blockIdx.x * BM;
    const int col0 = blockIdx.y * BN;

    f32x4 acc[4][4] = {};

    for (int kt = 0; kt < K; kt += 64) {
#pragma unroll
        for (int i = 0; i < 4; ++i) {
            int u = i * 256 + tid;
            int r = u >> 3, c16 = u & 7;
            int sc = ((c16 ^ (r & 7)) << 3);
            const u16* ga = A + (size_t)(row0 + r) * K + kt + sc;
            u16* la = &As[(size_t)(i * 256 + (w << 6)) * 8];
            __builtin_amdgcn_global_load_lds((const __attribute__((address_space(1))) void*)ga,
                                             (__attribute__((address_space(3))) void*)la, 16, 0, 0);
        }
#pragma unroll
        for (int i = 0; i < 4; ++i) {
            int u = i * 256 + tid;
            int r = u >> 3, c16 = u & 7;
            int sc = ((c16 ^ (r & 7)) << 3);
            const u16* gb = Bt + (size_t)(col0 + r) * K + kt + sc;
            u16* lb = &Bs[(size_t)(i * 256 + (w << 6)) * 8];
            __builtin_amdgcn_global_load_lds((const __attribute__((address_space(1))) void*)gb,
                                             (__attribute__((address_space(3))) void*)lb, 16, 0, 0);
        }
        __syncthreads();
#pragma unroll
        for (int ks = 0; ks < 2; ++ks) {
            s16x8 af[4], bfr[4];
#pragma unroll
            for (int m = 0; m < 4; ++m) {
                int ra = wr * 64 + m * 16 + (lane & 15);
                int c16 = ks * 4 + (lane >> 4);
                int off = ra * 64 + ((c16 ^ (ra & 7)) << 3);
                af[m] = *reinterpret_cast<const s16x8*>(&As[off]);
            }
#pragma unroll
            for (int n = 0; n < 4; ++n) {
                int rb = wc * 64 + n * 16 + (lane & 15);
                int c16 = ks * 4 + (lane >> 4);
                int off = rb * 64 + ((c16 ^ (rb & 7)) << 3);
                bfr[n] = *reinterpret_cast<const s16x8*>(&Bs[off]);
            }
#pragma unroll
            for (int m = 0; m < 4; ++m)
#pragma unroll
                for (int n = 0; n < 4; ++n)
                    acc[m][n] = __builtin_amdgcn_mfma_f32_16x16x32_bf16(af[m], bfr[n], acc[m][n], 0, 0, 0);
        }
        __syncthreads();
    }

    const int head = (blockIdx.y << 1) + wc;
    float asv[4], adv[4];
#pragma unroll
    for (int n = 0; n < 4; ++n) {
        asv[n] = att_s[head * 64 + n * 16 + (lane & 15)] * LOG2E;
        adv[n] = att_d[head * 64 + n * 16 + (lane & 15)] * LOG2E;
    }
#pragma unroll
    for (int m = 0; m < 4; ++m) {
        int growb = row0 + wr * 64 + m * 16 + (lane >> 4) * 4;
#pragma unroll
        for (int j = 0; j < 4; ++j) {
            int grow = growb + j;
            u16* orow = Hbf + (size_t)grow * 256 + col0 + wc * 64 + (lane & 15);
            float vs = 0.f, vd = 0.f;
#pragma unroll
            for (int n = 0; n < 4; ++n) {
                float v = acc[m][n][j];
                orow[n * 16] = f2bf(v);
                vs += v * asv[n];
                vd += v * adv[n];
            }
            vs += __shfl_xor(vs, 1); vd += __shfl_xor(vd, 1);
            vs += __shfl_xor(vs, 2); vd += __shfl_xor(vd, 2);
            vs += __shfl_xor(vs, 4); vd += __shfl_xor(vd, 4);
            vs += __shfl_xor(vs, 8); vd += __shfl_xor(vd, 8);
            if ((lane & 15) == 0) {
                a_s[grow * 4 + head] = vs;
                a_d[grow * 4 + head] = vd;
            }
        }
    }
}

// ---------------- online-softmax aggregate + fused pool, scalar-broadcast deep preload ----------------
// block = 512 thr = 8 waves = 8 consecutive nodes. Edge IDs are wave-uniform -> s_load broadcast
// (readfirstlane base + literal offsets); 16 row loads issue on SGPR+lane addresses, no bpermute
// in the address path. p-broadcast shuffles only in the consume phase (overlap in-flight loads).
__global__ __launch_bounds__(512) void k_agg(const u16* __restrict__ Hbf, const float* __restrict__ a_s,
                                             const float* __restrict__ a_d, const int* __restrict__ indptr,
                                             const int* __restrict__ esrc, const float* __restrict__ bias,
                                             const int* __restrict__ batch, u16* __restrict__ outbf,
                                             int* __restrict__ gbuf, int poolOff) {
    __shared__ float smax[8][256];
    __shared__ int sb[8];
    const int nodeBase = blockIdx.x * 8;
    const int wv = threadIdx.x >> 6;
    const int wid = nodeBase + wv;
    const int lane = threadIdx.x & 63;
    const int h = lane >> 4;
    const int eidx = lane & 15;
    const int pbase = lane & 48;

    if (threadIdx.x < 8) sb[threadIdx.x] = batch[nodeBase + threadIdx.x];
    __syncthreads();

    int beg = indptr[wid];
    int dcount = indptr[wid + 1] - beg;
    float ad = a_d[wid * 4 + h];
    float mx = -3.0e38f, ssum = 0.f;
    float ax = 0.f, ay = 0.f, az = 0.f, aw = 0.f;

    for (int cb = 0; cb < dcount; cb += 16) {
        const int cnt = min(16, dcount - cb);                     // wave-uniform
        const int baseu = __builtin_amdgcn_readfirstlane(beg + cb); // SGPR
        // per-lane score chain: esrc -> a_s gather (issued first; its wait is a counted vmcnt)
        int s = esrc[baseu + min(eidx, cnt - 1)];
        float asg = a_s[s * 4 + h];
        // scalar-broadcast edge ids (s_load_dword xN, one lgkmcnt wait)
#define GETS(k) int sk##k = esrc[baseu + min(k, cnt - 1)];
        GETS(0)  GETS(1)  GETS(2)  GETS(3)  GETS(4)  GETS(5)  GETS(6)  GETS(7)
        GETS(8)  GETS(9)  GETS(10) GETS(11) GETS(12) GETS(13) GETS(14) GETS(15)
#undef GETS
        // issue all row loads (uniform scalar guards, SGPR base + lane offset)
        ushort4 hv0, hv1, hv2, hv3, hv4, hv5, hv6, hv7,
                hv8, hv9, hv10, hv11, hv12, hv13, hv14, hv15;
#define LOADH(k)                                                                          \
        if (k < cnt) hv##k = *reinterpret_cast<const ushort4*>(Hbf + (size_t)sk##k * 256 + lane * 4);
        LOADH(0)  LOADH(1)  LOADH(2)  LOADH(3)
        LOADH(4)  LOADH(5)  LOADH(6)  LOADH(7)
        LOADH(8)  LOADH(9)  LOADH(10) LOADH(11)
        LOADH(12) LOADH(13) LOADH(14) LOADH(15)
#undef LOADH
        // softmax math overlaps in-flight row loads
        float el = (eidx < cnt) ? asg + ad : -3.0e38f;
        el = fmaxf(el, 0.2f * el);
        float cm = el;
        cm = fmaxf(cm, __shfl_xor(cm, 1));
        cm = fmaxf(cm, __shfl_xor(cm, 2));
        cm = fmaxf(cm, __shfl_xor(cm, 4));
        cm = fmaxf(cm, __shfl_xor(cm, 8));
        float nm = fmaxf(mx, cm);
        if (__any(nm > mx)) {
            float corr = exp2f(mx - nm);
            ssum *= corr; ax *= corr; ay *= corr; az *= corr; aw *= corr;
            mx = nm;
        }
        float p = exp2f(el - mx);
        float cs = p;
        cs += __shfl_xor(cs, 1);
        cs += __shfl_xor(cs, 2);
        cs += __shfl_xor(cs, 4);
        cs += __shfl_xor(cs, 8);
        ssum += cs;
        // consume rows in issue order
#define ACCH(k)                                                                           \
        if (k < cnt) {                                                                    \
            float pk = __shfl(p, pbase | k);                                              \
            ax += pk * bf2f(hv##k.x); ay += pk * bf2f(hv##k.y);                           \
            az += pk * bf2f(hv##k.z); aw += pk * bf2f(hv##k.w);                           \
        }
        ACCH(0)  ACCH(1)  ACCH(2)  ACCH(3)
        ACCH(4)  ACCH(5)  ACCH(6)  ACCH(7)
        ACCH(8)  ACCH(9)  ACCH(10) ACCH(11)
        ACCH(12) ACCH(13) ACCH(14) ACCH(15)
#undef ACCH
    }

    float inv = 1.0f / ssum;
    const float4 bv = *reinterpret_cast<const float4*>(bias + lane * 4);
    float o0 = fmaxf(ax * inv + bv.x, 0.f);
    float o1 = fmaxf(ay * inv + bv.y, 0.f);
    float o2 = fmaxf(az * inv + bv.z, 0.f);
    float o3 = fmaxf(aw * inv + bv.w, 0.f);
    ushort4 ob; ob.x = f2bf(o0); ob.y = f2bf(o1); ob.z = f2bf(o2); ob.w = f2bf(o3);
    *reinterpret_cast<ushort4*>(outbf + (size_t)wid * 256 + lane * 4) = ob;

    // pool: LDS row store (no atomics)
    *reinterpret_cast<float4*>(&smax[wv][lane * 4]) = make_float4(o0, o1, o2, o3);
    int slot = sb[wv] - sb[0];
    if (slot >= 2) {   // rare: >2 graphs in an 8-node window
        int* cell = &gbuf[sb[wv] * GCOLS + poolOff + lane * 4];
        atomicMax(cell,     __float_as_int(o0));
        atomicMax(cell + 1, __float_as_int(o1));
        atomicMax(cell + 2, __float_as_int(o2));
        atomicMax(cell + 3, __float_as_int(o3));
    }
    __syncthreads();

    // flush: 512 threads = 2 graph slots x 256 channels
    int slotf = threadIdx.x >> 8;
    int c = threadIdx.x & 255;
    int gtar = sb[0] + slotf;
    float m = 0.f;
#pragma unroll
    for (int n = 0; n < 8; ++n)
        if (sb[n] == gtar) m = fmaxf(m, smax[n][c]);
    if (m > 0.f) atomicMax(&gbuf[gtar * GCOLS + poolOff + c], __float_as_int(m));
}

// ---------------- fused head: 1024 thr, k-split 4-ways ----------------
__global__ __launch_bounds__(1024) void k_head(const int* __restrict__ gbuf,
                                               const float* __restrict__ aggW, const float* __restrict__ aggb,
                                               const float* __restrict__ muW, const float* __restrict__ mub,
                                               const float* __restrict__ varW, const float* __restrict__ varb,
                                               float* __restrict__ out) {
    __shared__ float part[4][256];
    __shared__ float lat[LATD];
    int gi = blockIdx.x;
    int j = threadIdx.x & 255, ks = threadIdx.x >> 8;
    const float* g = (const float*)gbuf + (size_t)gi * GCOLS;
    float acc = 0.f;
    int k0 = ks * 208;
    for (int k = k0; k < k0 + 208; ++k) acc += g[k] * aggW[k * 256 + j];
    part[ks][j] = acc;
    __syncthreads();
    if (ks == 0) lat[j] = part[0][j] + part[1][j] + part[2][j] + part[3][j] + aggb[j];
    __syncthreads();
    const float* W = (ks < 2) ? muW : varW;
    int kb = (ks & 1) * 128;
    float am = 0.f;
    for (int k = kb; k < kb + 128; ++k) am += lat[k] * W[k * 256 + j];
    part[ks][j] = am;
    __syncthreads();
    if (ks == 0) out[(size_t)gi * 256 + j] = part[0][j] + part[1][j] + mub[j];
    else if (ks == 1) out[(size_t)GG * 256 + (size_t)gi * 256 + j] = part[2][j] + part[3][j] + varb[j];
}

extern "C" void kernel_launch(void* const* d_in, const int* in_sizes, int n_in,
                              void* d_out, int out_size, void* d_ws, size_t ws_size,
                              hipStream_t stream) {
    const float* bf   = (const float*)d_in[0];
    const int*   ei   = (const int*)d_in[1];
    const int*   batch= (const int*)d_in[2];
    const float* bf_W = (const float*)d_in[3];
    const float* bf_b = (const float*)d_in[4];
    const float* W1   = (const float*)d_in[5];
    const float* as1  = (const float*)d_in[6];
    const float* ad1  = (const float*)d_in[7];
    const float* b1   = (const float*)d_in[8];
    const float* W2   = (const float*)d_in[9];
    const float* as2  = (const float*)d_in[10];
    const float* ad2  = (const float*)d_in[11];
    const float* b2   = (const float*)d_in[12];
    const float* W3   = (const float*)d_in[13];
    const float* as3  = (const float*)d_in[14];
    const float* ad3  = (const float*)d_in[15];
    const float* b3   = (const float*)d_in[16];
    const float* aggW = (const float*)d_in[17];
    const float* aggb = (const float*)d_in[18];
    const float* muW  = (const float*)d_in[19];
    const float* mub  = (const float*)d_in[20];
    const float* varW = (const float*)d_in[21];
    const float* varb = (const float*)d_in[22];
    float* out = (float*)d_out;

    size_t off = 0;
    auto alloc = [&](size_t bytes) -> char* {
        char* p = (char*)d_ws + off;
        off += (bytes + 255) & ~(size_t)255;
        return p;
    };
    int*   counts  = (int*)alloc((size_t)(NN + GG * GCOLS) * 4);
    int*   gbuf    = counts + NN;
    u16*   Hbf     = (u16*)alloc((size_t)NPAD * 256 * 2);
    u16*   n0bf    = (u16*)alloc((size_t)NPAD * 64 * 2);
    u16*   nbf     = (u16*)alloc((size_t)NPAD * 256 * 2);
    float* a_s     = (float*)alloc((size_t)NPAD * 4 * 4);
    float* a_d     = (float*)alloc((size_t)NPAD * 4 * 4);
    int*   scanned = (int*)alloc((size_t)NN * 4);
    int*   bsums   = (int*)alloc(256 * 4);
    int*   indptr  = (int*)alloc((size_t)(NN + 1) * 4);
    int*   fill    = (int*)alloc((size_t)NN * 4);
    int*   esrc    = (int*)alloc((size_t)(ETOT + 16) * 4);   // +16 slop for clamped scalar reads
    u16*   Wt1     = (u16*)alloc((size_t)256 * 64 * 2);
    u16*   Wt2     = (u16*)alloc((size_t)256 * 256 * 2);
    u16*   Wt3     = (u16*)alloc((size_t)256 * 256 * 2);

    hipMemsetAsync(counts, 0, (size_t)(NN + GG * GCOLS) * 4, stream);

    k_prep<<<2336, 256, 0, stream>>>(W1, W2, W3, Wt1, Wt2, Wt3,
                                     bf, bf_W, bf_b, batch, n0bf, gbuf,
                                     ei, counts, nbf);

    k_scan_block<<<NB_SCAN, 256, 0, stream>>>(counts, scanned, bsums, NN);
    k_scan_add2<<<NB_SCAN, 256, 0, stream>>>(scanned, bsums, indptr, fill);
    k_fill<<<(ETOT + 255) / 256, 256, 0, stream>>>(ei, indptr, fill, esrc);

    dim3 ggrid(NPAD / BM, 256 / BN);     // (391, 2)
    const int AB = NN / 8;               // 6250

    // ---- layer 1 (K=64) ----
    k_gemm_mfma<<<ggrid, 256, 0, stream>>>(n0bf, Wt1, as1, ad1, Hbf, a_s, a_d, 64);
    k_agg<<<AB, 512, 0, stream>>>(Hbf, a_s, a_d, indptr, esrc, b1, batch, nbf, gbuf, 64);

    // ---- layer 2 (K=256) ----
    k_gemm_mfma<<<ggrid, 256, 0, stream>>>(nbf, Wt2, as2, ad2, Hbf, a_s, a_d, 256);
    k_agg<<<AB, 512, 0, stream>>>(Hbf, a_s, a_d, indptr, esrc, b2, batch, nbf, gbuf, 320);

    // ---- layer 3 (K=256) ----
    k_gemm_mfma<<<ggrid, 256, 0, stream>>>(nbf, Wt3, as3, ad3, Hbf, a_s, a_d, 256);
    k_agg<<<AB, 512, 0, stream>>>(Hbf, a_s, a_d, indptr, esrc, b3, batch, nbf, gbuf, 576);

    // ---- head ----
    k_head<<<GG, 1024, 0, stream>>>(gbuf, aggW, aggb, muW, mub, varW, varb, out);
}

// Round 9
// 265.418 us; speedup vs baseline: 1.2284x; 1.2284x over previous
//
#include <hip/hip_runtime.h>
#include <hip/hip_bf16.h>

#define NN 50000
#define NPAD 50048              // 391 * 128
#define EE 300000
#define ETOT (EE + NN)          // 350000 edges incl self-loops
#define GG 64
#define GCOLS 832               // 64 + 3*256
#define LATD 256
#define BM 128
#define BN 128
#define NB_SCAN 196             // (NN+255)/256
#define LOG2E 1.4426950408889634f

typedef unsigned short u16;
typedef short s16x8 __attribute__((ext_vector_type(8)));
typedef float f32x4 __attribute__((ext_vector_type(4)));

__device__ __forceinline__ u16 f2bf(float f) {
    union { float f; unsigned u; } v; v.f = f;
    unsigned r = v.u + 0x7FFFu + ((v.u >> 16) & 1u);
    return (u16)(r >> 16);
}
__device__ __forceinline__ float bf2f(u16 u) {
    union { unsigned u; float f; } v; v.u = ((unsigned)u) << 16;
    return v.f;
}

// ---------------- prep: weight transposes | n0+pool | edge count | pad zero ----------------
__global__ __launch_bounds__(256) void k_prep(const float* __restrict__ W1, const float* __restrict__ W2,
                                              const float* __restrict__ W3, u16* __restrict__ Wt1,
                                              u16* __restrict__ Wt2, u16* __restrict__ Wt3,
                                              const float* __restrict__ bf, const float* __restrict__ Wb,
                                              const float* __restrict__ bb, const int* __restrict__ batch,
                                              u16* __restrict__ n0bf, int* __restrict__ gbuf,
                                              const int* __restrict__ ei, int* __restrict__ counts,
                                              u16* __restrict__ nbf) {
    int b = blockIdx.x;
    if (b < 576) {
        int idx = b * 256 + threadIdx.x;
        if (idx < 16384) {
            int n = idx >> 6, k = idx & 63;
            Wt1[idx] = f2bf(W1[k * 256 + n]);
        } else if (idx < 81920) {
            int t = idx - 16384; int n = t >> 8, k = t & 255;
            Wt2[t] = f2bf(W2[k * 256 + n]);
        } else {
            int t = idx - 81920; int n = t >> 8, k = t & 255;
            Wt3[t] = f2bf(W3[k * 256 + n]);
        }
    } else if (b < 967) {
        int c = threadIdx.x & 63;
        int sub = threadIdx.x >> 6;
        int base = (b - 576) * 128;
        int end = min(base + 128, NN);
        float w0 = Wb[c], w1 = Wb[64 + c], w2 = Wb[128 + c], w3 = Wb[192 + c], w4 = Wb[256 + c], bb_ = bb[c];
        float mx = 0.f;
        int curg = -1;
        for (int n = base + sub; n < end; n += 4) {
            const float* r = bf + (size_t)n * 5;
            float v = bb_ + r[0] * w0 + r[1] * w1 + r[2] * w2 + r[3] * w3 + r[4] * w4;
            v = fmaxf(v, 0.f);
            n0bf[(size_t)n * 64 + c] = f2bf(v);
            int g = batch[n];
            if (g != curg) {
                if (curg >= 0) atomicMax(&gbuf[curg * GCOLS + c], __float_as_int(mx));
                mx = 0.f; curg = g;
            }
            mx = fmaxf(mx, v);
        }
        if (curg >= 0) atomicMax(&gbuf[curg * GCOLS + c], __float_as_int(mx));
    } else if (b < 2335) {
        int e = (b - 967) * 256 + threadIdx.x;
        if (e < ETOT) {
            int d = (e < EE) ? ei[EE + e] : (e - EE);
            atomicAdd(&counts[d], 1);
        }
    } else {
        u16* p0 = n0bf + (size_t)NN * 64;
        for (int i = threadIdx.x; i < (NPAD - NN) * 64; i += 256) p0[i] = 0;
        u16* p1 = nbf + (size_t)NN * 256;
        for (int i = threadIdx.x; i < (NPAD - NN) * 256; i += 256) p1[i] = 0;
    }
}

// ---------------- CSR scan ----------------
__global__ __launch_bounds__(256) void k_scan_block(const int* __restrict__ counts, int* __restrict__ scanned,
                                                    int* __restrict__ bsums, int n) {
    __shared__ int sh[256];
    int i = blockIdx.x * 256 + threadIdx.x;
    int v = (i < n) ? counts[i] : 0;
    sh[threadIdx.x] = v; __syncthreads();
    for (int d = 1; d < 256; d <<= 1) {
        int t = (threadIdx.x >= d) ? sh[threadIdx.x - d] : 0;
        __syncthreads();
        sh[threadIdx.x] += t;
        __syncthreads();
    }
    if (i < n) scanned[i] = sh[threadIdx.x] - v;
    if (threadIdx.x == 255) bsums[blockIdx.x] = sh[255];
}

__global__ __launch_bounds__(256) void k_scan_add2(const int* __restrict__ scanned, const int* __restrict__ bsums,
                                                   int* __restrict__ indptr, int* __restrict__ fill) {
    __shared__ int sh[256];
    int t = threadIdx.x;
    int v = (t < NB_SCAN) ? bsums[t] : 0;
    sh[t] = v; __syncthreads();
    for (int d = 1; d < 256; d <<= 1) {
        int u = (t >= d) ? sh[t - d] : 0;
        __syncthreads();
        sh[t] += u;
        __syncthreads();
    }
    int bix = blockIdx.x;
    int boff = (bix == 0) ? 0 : sh[bix - 1];
    int i = bix * 256 + t;
    if (i < NN) { indptr[i] = scanned[i] + boff; fill[i] = 0; }
    if (i == 0) indptr[NN] = ETOT;
}

__global__ __launch_bounds__(256) void k_fill(const int* __restrict__ ei, const int* __restrict__ indptr,
                                              int* __restrict__ fill, int* __restrict__ esrc) {
    int e = blockIdx.x * 256 + threadIdx.x;
    if (e >= ETOT) return;
    int s, d;
    if (e < EE) { s = ei[e]; d = ei[EE + e]; } else { s = d = e - EE; }
    int pos = atomicAdd(&fill[d], 1);
    esrc[indptr[d] + pos] = s;
}

// ---------------- bf16 MFMA GEMM + fused a_s/a_d epilogue (scores pre-scaled by log2e) ----------------
__global__ __launch_bounds__(256) void k_gemm_mfma(const u16* __restrict__ A,
                                                   const u16* __restrict__ Bt,
                                                   const float* __restrict__ att_s,
                                                   const float* __restrict__ att_d,
                                                   u16* __restrict__ Hbf,
                                                   float* __restrict__ a_s,
                                                   float* __restrict__ a_d,
                                                   int K) {
    __shared__ __align__(16) u16 As[128 * 64];
    __shared__ __align__(16) u16 Bs[128 * 64];
    const int tid = threadIdx.x;
    const int lane = tid & 63;
    const int w = tid >> 6;
    const int wr = w >> 1, wc = w & 1;
    const int row0 = blockIdx.x * BM;
    const int col0 = blockIdx.y * BN;

    f32x4 acc[4][4] = {};

    for (int kt = 0; kt < K; kt += 64) {
#pragma unroll
        for (int i = 0; i < 4; ++i) {
            int u = i * 256 + tid;
            int r = u >> 3, c16 = u & 7;
            int sc = ((c16 ^ (r & 7)) << 3);
            const u16* ga = A + (size_t)(row0 + r) * K + kt + sc;
            u16* la = &As[(size_t)(i * 256 + (w << 6)) * 8];
            __builtin_amdgcn_global_load_lds((const __attribute__((address_space(1))) void*)ga,
                                             (__attribute__((address_space(3))) void*)la, 16, 0, 0);
        }
#pragma unroll
        for (int i = 0; i < 4; ++i) {
            int u = i * 256 + tid;
            int r = u >> 3, c16 = u & 7;
            int sc = ((c16 ^ (r & 7)) << 3);
            const u16* gb = Bt + (size_t)(col0 + r) * K + kt + sc;
            u16* lb = &Bs[(size_t)(i * 256 + (w << 6)) * 8];
            __builtin_amdgcn_global_load_lds((const __attribute__((address_space(1))) void*)gb,
                                             (__attribute__((address_space(3))) void*)lb, 16, 0, 0);
        }
        __syncthreads();
#pragma unroll
        for (int ks = 0; ks < 2; ++ks) {
            s16x8 af[4], bfr[4];
#pragma unroll
            for (int m = 0; m < 4; ++m) {
                int ra = wr * 64 + m * 16 + (lane & 15);
                int c16 = ks * 4 + (lane >> 4);
                int off = ra * 64 + ((c16 ^ (ra & 7)) << 3);
                af[m] = *reinterpret_cast<const s16x8*>(&As[off]);
            }
#pragma unroll
            for (int n = 0; n < 4; ++n) {
                int rb = wc * 64 + n * 16 + (lane & 15);
                int c16 = ks * 4 + (lane >> 4);
                int off = rb * 64 + ((c16 ^ (rb & 7)) << 3);
                bfr[n] = *reinterpret_cast<const s16x8*>(&Bs[off]);
            }
#pragma unroll
            for (int m = 0; m < 4; ++m)
#pragma unroll
                for (int n = 0; n < 4; ++n)
                    acc[m][n] = __builtin_amdgcn_mfma_f32_16x16x32_bf16(af[m], bfr[n], acc[m][n], 0, 0, 0);
        }
        __syncthreads();
    }

    const int head = (blockIdx.y << 1) + wc;
    float asv[4], adv[4];
#pragma unroll
    for (int n = 0; n < 4; ++n) {
        asv[n] = att_s[head * 64 + n * 16 + (lane & 15)] * LOG2E;
        adv[n] = att_d[head * 64 + n * 16 + (lane & 15)] * LOG2E;
    }
#pragma unroll
    for (int m = 0; m < 4; ++m) {
        int growb = row0 + wr * 64 + m * 16 + (lane >> 4) * 4;
#pragma unroll
        for (int j = 0; j < 4; ++j) {
            int grow = growb + j;
            u16* orow = Hbf + (size_t)grow * 256 + col0 + wc * 64 + (lane & 15);
            float vs = 0.f, vd = 0.f;
#pragma unroll
            for (int n = 0; n < 4; ++n) {
                float v = acc[m][n][j];
                orow[n * 16] = f2bf(v);
                vs += v * asv[n];
                vd += v * adv[n];
            }
            vs += __shfl_xor(vs, 1); vd += __shfl_xor(vd, 1);
            vs += __shfl_xor(vs, 2); vd += __shfl_xor(vd, 2);
            vs += __shfl_xor(vs, 4); vd += __shfl_xor(vd, 4);
            vs += __shfl_xor(vs, 8); vd += __shfl_xor(vd, 8);
            if ((lane & 15) == 0) {
                a_s[grow * 4 + head] = vs;
                a_d[grow * 4 + head] = vd;
            }
        }
    }
}

// ---------------- two-phase online-softmax aggregate + fused pool (round-5 verified structure) ----------------
// block = 1024 thr = 16 waves = 16 consecutive nodes (batch-sorted); LDS dedup pool table.
__global__ __launch_bounds__(1024) void k_agg(const u16* __restrict__ Hbf, const float* __restrict__ a_s,
                                              const float* __restrict__ a_d, const int* __restrict__ indptr,
                                              const int* __restrict__ esrc, const float* __restrict__ bias,
                                              const int* __restrict__ batch, u16* __restrict__ outbf,
                                              int* __restrict__ gbuf, int poolOff) {
    __shared__ int lpool[2][256];
    if (threadIdx.x < 512) lpool[threadIdx.x >> 8][threadIdx.x & 255] = 0;
    __syncthreads();

    const int nodeBase = blockIdx.x * 16;
    const int wv = threadIdx.x >> 6;
    const int wid = nodeBase + wv;
    const int lane = threadIdx.x & 63;
    const int h = lane >> 4;
    const int eidx = lane & 15;
    const bool active = wid < NN;

    if (active) {
        int beg = indptr[wid];
        int dcount = indptr[wid + 1] - beg;
        float ad = a_d[wid * 4 + h];
        float mx = -3.0e38f, ssum = 0.f;
        float ax = 0.f, ay = 0.f, az = 0.f, aw = 0.f;

        for (int cb = 0; cb < dcount; cb += 16) {
            int cnt = min(16, dcount - cb);
            // ---- phase A: scores for up to 16 edges x 4 heads across the wave ----
            int s = (eidx < cnt) ? esrc[beg + cb + eidx] : 0;
            float el = (eidx < cnt) ? a_s[s * 4 + h] + ad : -3.0e38f;
            el = fmaxf(el, 0.2f * el);
            float cm = el;
            cm = fmaxf(cm, __shfl_xor(cm, 1));
            cm = fmaxf(cm, __shfl_xor(cm, 2));
            cm = fmaxf(cm, __shfl_xor(cm, 4));
            cm = fmaxf(cm, __shfl_xor(cm, 8));
            float nm = fmaxf(mx, cm);
            if (__any(nm > mx)) {
                float corr = exp2f(mx - nm);
                ssum *= corr; ax *= corr; ay *= corr; az *= corr; aw *= corr;
                mx = nm;
            }
            float p = exp2f(el - mx);
            float cs = p;
            cs += __shfl_xor(cs, 1);
            cs += __shfl_xor(cs, 2);
            cs += __shfl_xor(cs, 4);
            cs += __shfl_xor(cs, 8);
            ssum += cs;
            // ---- phase B: PV with p broadcast ----
            int e2 = 0;
            for (; e2 + 2 <= cnt; e2 += 2) {
                int s0 = __shfl(s, e2), s1 = __shfl(s, e2 + 1);
                float p0 = __shfl(p, (lane & 48) | e2);
                float p1 = __shfl(p, (lane & 48) | (e2 + 1));
                const ushort4 h0 = *reinterpret_cast<const ushort4*>(Hbf + (size_t)s0 * 256 + lane * 4);
                const ushort4 h1 = *reinterpret_cast<const ushort4*>(Hbf + (size_t)s1 * 256 + lane * 4);
                ax += p0 * bf2f(h0.x) + p1 * bf2f(h1.x);
                ay += p0 * bf2f(h0.y) + p1 * bf2f(h1.y);
                az += p0 * bf2f(h0.z) + p1 * bf2f(h1.z);
                aw += p0 * bf2f(h0.w) + p1 * bf2f(h1.w);
            }
            if (e2 < cnt) {
                int s0 = __shfl(s, e2);
                float p0 = __shfl(p, (lane & 48) | e2);
                const ushort4 h0 = *reinterpret_cast<const ushort4*>(Hbf + (size_t)s0 * 256 + lane * 4);
                ax += p0 * bf2f(h0.x);
                ay += p0 * bf2f(h0.y);
                az += p0 * bf2f(h0.z);
                aw += p0 * bf2f(h0.w);
            }
        }

        float inv = 1.0f / ssum;
        const float4 bv = *reinterpret_cast<const float4*>(bias + lane * 4);
        float o0 = fmaxf(ax * inv + bv.x, 0.f);
        float o1 = fmaxf(ay * inv + bv.y, 0.f);
        float o2 = fmaxf(az * inv + bv.z, 0.f);
        float o3 = fmaxf(aw * inv + bv.w, 0.f);
        ushort4 ob; ob.x = f2bf(o0); ob.y = f2bf(o1); ob.z = f2bf(o2); ob.w = f2bf(o3);
        *reinterpret_cast<ushort4*>(outbf + (size_t)wid * 256 + lane * 4) = ob;

        // fused pool
        int g = batch[wid];
        int g0 = batch[nodeBase];
        int slot = g - g0;
        int c4 = lane * 4;
        if (slot < 2) {
            atomicMax(&lpool[slot][c4],     __float_as_int(o0));
            atomicMax(&lpool[slot][c4 + 1], __float_as_int(o1));
            atomicMax(&lpool[slot][c4 + 2], __float_as_int(o2));
            atomicMax(&lpool[slot][c4 + 3], __float_as_int(o3));
        } else {
            int* cell = &gbuf[g * GCOLS + poolOff + c4];
            atomicMax(cell,     __float_as_int(o0));
            atomicMax(cell + 1, __float_as_int(o1));
            atomicMax(cell + 2, __float_as_int(o2));
            atomicMax(cell + 3, __float_as_int(o3));
        }
    }
    __syncthreads();
    if (threadIdx.x < 512) {
        int slot = threadIdx.x >> 8, c = threadIdx.x & 255;
        int v = lpool[slot][c];
        if (v != 0) {
            int g0 = batch[nodeBase];
            atomicMax(&gbuf[(g0 + slot) * GCOLS + poolOff + c], v);
        }
    }
}

// ---------------- fused head: 1024 thr, k-split 4-ways ----------------
__global__ __launch_bounds__(1024) void k_head(const int* __restrict__ gbuf,
                                               const float* __restrict__ aggW, const float* __restrict__ aggb,
                                               const float* __restrict__ muW, const float* __restrict__ mub,
                                               const float* __restrict__ varW, const float* __restrict__ varb,
                                               float* __restrict__ out) {
    __shared__ float part[4][256];
    __shared__ float lat[LATD];
    int gi = blockIdx.x;
    int j = threadIdx.x & 255, ks = threadIdx.x >> 8;
    const float* g = (const float*)gbuf + (size_t)gi * GCOLS;
    float acc = 0.f;
    int k0 = ks * 208;
    for (int k = k0; k < k0 + 208; ++k) acc += g[k] * aggW[k * 256 + j];
    part[ks][j] = acc;
    __syncthreads();
    if (ks == 0) lat[j] = part[0][j] + part[1][j] + part[2][j] + part[3][j] + aggb[j];
    __syncthreads();
    const float* W = (ks < 2) ? muW : varW;
    int kb = (ks & 1) * 128;
    float am = 0.f;
    for (int k = kb; k < kb + 128; ++k) am += lat[k] * W[k * 256 + j];
    part[ks][j] = am;
    __syncthreads();
    if (ks == 0) out[(size_t)gi * 256 + j] = part[0][j] + part[1][j] + mub[j];
    else if (ks == 1) out[(size_t)GG * 256 + (size_t)gi * 256 + j] = part[2][j] + part[3][j] + varb[j];
}

extern "C" void kernel_launch(void* const* d_in, const int* in_sizes, int n_in,
                              void* d_out, int out_size, void* d_ws, size_t ws_size,
                              hipStream_t stream) {
    const float* bf   = (const float*)d_in[0];
    const int*   ei   = (const int*)d_in[1];
    const int*   batch= (const int*)d_in[2];
    const float* bf_W = (const float*)d_in[3];
    const float* bf_b = (const float*)d_in[4];
    const float* W1   = (const float*)d_in[5];
    const float* as1  = (const float*)d_in[6];
    const float* ad1  = (const float*)d_in[7];
    const float* b1   = (const float*)d_in[8];
    const float* W2   = (const float*)d_in[9];
    const float* as2  = (const float*)d_in[10];
    const float* ad2  = (const float*)d_in[11];
    const float* b2   = (const float*)d_in[12];
    const float* W3   = (const float*)d_in[13];
    const float* as3  = (const float*)d_in[14];
    const float* ad3  = (const float*)d_in[15];
    const float* b3   = (const float*)d_in[16];
    const float* aggW = (const float*)d_in[17];
    const float* aggb = (const float*)d_in[18];
    const float* muW  = (const float*)d_in[19];
    const float* mub  = (const float*)d_in[20];
    const float* varW = (const float*)d_in[21];
    const float* varb = (const float*)d_in[22];
    float* out = (float*)d_out;

    size_t off = 0;
    auto alloc = [&](size_t bytes) -> char* {
        char* p = (char*)d_ws + off;
        off += (bytes + 255) & ~(size_t)255;
        return p;
    };
    int*   counts  = (int*)alloc((size_t)(NN + GG * GCOLS) * 4);
    int*   gbuf    = counts + NN;
    u16*   Hbf     = (u16*)alloc((size_t)NPAD * 256 * 2);
    u16*   n0bf    = (u16*)alloc((size_t)NPAD * 64 * 2);
    u16*   nbf     = (u16*)alloc((size_t)NPAD * 256 * 2);
    float* a_s     = (float*)alloc((size_t)NPAD * 4 * 4);
    float* a_d     = (float*)alloc((size_t)NPAD * 4 * 4);
    int*   scanned = (int*)alloc((size_t)NN * 4);
    int*   bsums   = (int*)alloc(256 * 4);
    int*   indptr  = (int*)alloc((size_t)(NN + 1) * 4);
    int*   fill    = (int*)alloc((size_t)NN * 4);
    int*   esrc    = (int*)alloc((size_t)(ETOT + 16) * 4);
    u16*   Wt1     = (u16*)alloc((size_t)256 * 64 * 2);
    u16*   Wt2     = (u16*)alloc((size_t)256 * 256 * 2);
    u16*   Wt3     = (u16*)alloc((size_t)256 * 256 * 2);

    hipMemsetAsync(counts, 0, (size_t)(NN + GG * GCOLS) * 4, stream);

    k_prep<<<2336, 256, 0, stream>>>(W1, W2, W3, Wt1, Wt2, Wt3,
                                     bf, bf_W, bf_b, batch, n0bf, gbuf,
                                     ei, counts, nbf);

    k_scan_block<<<NB_SCAN, 256, 0, stream>>>(counts, scanned, bsums, NN);
    k_scan_add2<<<NB_SCAN, 256, 0, stream>>>(scanned, bsums, indptr, fill);
    k_fill<<<(ETOT + 255) / 256, 256, 0, stream>>>(ei, indptr, fill, esrc);

    dim3 ggrid(NPAD / BM, 256 / BN);     // (391, 2)
    const int AB = NN / 16;              // 3125

    // ---- layer 1 (K=64) ----
    k_gemm_mfma<<<ggrid, 256, 0, stream>>>(n0bf, Wt1, as1, ad1, Hbf, a_s, a_d, 64);
    k_agg<<<AB, 1024, 0, stream>>>(Hbf, a_s, a_d, indptr, esrc, b1, batch, nbf, gbuf, 64);

    // ---- layer 2 (K=256) ----
    k_gemm_mfma<<<ggrid, 256, 0, stream>>>(nbf, Wt2, as2, ad2, Hbf, a_s, a_d, 256);
    k_agg<<<AB, 1024, 0, stream>>>(Hbf, a_s, a_d, indptr, esrc, b2, batch, nbf, gbuf, 320);

    // ---- layer 3 (K=256) ----
    k_gemm_mfma<<<ggrid, 256, 0, stream>>>(nbf, Wt3, as3, ad3, Hbf, a_s, a_d, 256);
    k_agg<<<AB, 1024, 0, stream>>>(Hbf, a_s, a_d, indptr, esrc, b3, batch, nbf, gbuf, 576);

    // ---- head ----
    k_head<<<GG, 1024, 0, stream>>>(gbuf, aggW, aggb, muW, mub, varW, varb, out);
}

// Round 10
// 257.921 us; speedup vs baseline: 1.2641x; 1.0291x over previous
//
#include <hip/hip_runtime.h>
#include <hip/hip_bf16.h>

#define NN 50000
#define NPAD 50048              // 391 * 128
#define EE 300000
#define ETOT (EE + NN)          // 350000 edges incl self-loops
#define GG 64
#define GCOLS 832               // 64 + 3*256
#define LATD 256
#define BM 128
#define BN 128
#define NB_SCAN 196             // (NN+255)/256
#define LOG2E 1.4426950408889634f

typedef unsigned short u16;
typedef short s16x8 __attribute__((ext_vector_type(8)));
typedef float f32x4 __attribute__((ext_vector_type(4)));

__device__ __forceinline__ u16 f2bf(float f) {
    union { float f; unsigned u; } v; v.f = f;
    unsigned r = v.u + 0x7FFFu + ((v.u >> 16) & 1u);
    return (u16)(r >> 16);
}
__device__ __forceinline__ float bf2f(u16 u) {
    union { unsigned u; float f; } v; v.u = ((unsigned)u) << 16;
    return v.f;
}

// ---------------- prep: weight transposes | n0+pool | edge count | pad zero ----------------
__global__ __launch_bounds__(256) void k_prep(const float* __restrict__ W1, const float* __restrict__ W2,
                                              const float* __restrict__ W3, u16* __restrict__ Wt1,
                                              u16* __restrict__ Wt2, u16* __restrict__ Wt3,
                                              const float* __restrict__ bf, const float* __restrict__ Wb,
                                              const float* __restrict__ bb, const int* __restrict__ batch,
                                              u16* __restrict__ n0bf, int* __restrict__ gbuf,
                                              const int* __restrict__ ei, int* __restrict__ counts,
                                              u16* __restrict__ nbf) {
    int b = blockIdx.x;
    if (b < 576) {
        int idx = b * 256 + threadIdx.x;
        if (idx < 16384) {
            int n = idx >> 6, k = idx & 63;
            Wt1[idx] = f2bf(W1[k * 256 + n]);
        } else if (idx < 81920) {
            int t = idx - 16384; int n = t >> 8, k = t & 255;
            Wt2[t] = f2bf(W2[k * 256 + n]);
        } else {
            int t = idx - 81920; int n = t >> 8, k = t & 255;
            Wt3[t] = f2bf(W3[k * 256 + n]);
        }
    } else if (b < 967) {
        int c = threadIdx.x & 63;
        int sub = threadIdx.x >> 6;
        int base = (b - 576) * 128;
        int end = min(base + 128, NN);
        float w0 = Wb[c], w1 = Wb[64 + c], w2 = Wb[128 + c], w3 = Wb[192 + c], w4 = Wb[256 + c], bb_ = bb[c];
        float mx = 0.f;
        int curg = -1;
        for (int n = base + sub; n < end; n += 4) {
            const float* r = bf + (size_t)n * 5;
            float v = bb_ + r[0] * w0 + r[1] * w1 + r[2] * w2 + r[3] * w3 + r[4] * w4;
            v = fmaxf(v, 0.f);
            n0bf[(size_t)n * 64 + c] = f2bf(v);
            int g = batch[n];
            if (g != curg) {
                if (curg >= 0) atomicMax(&gbuf[curg * GCOLS + c], __float_as_int(mx));
                mx = 0.f; curg = g;
            }
            mx = fmaxf(mx, v);
        }
        if (curg >= 0) atomicMax(&gbuf[curg * GCOLS + c], __float_as_int(mx));
    } else if (b < 2335) {
        int e = (b - 967) * 256 + threadIdx.x;
        if (e < ETOT) {
            int d = (e < EE) ? ei[EE + e] : (e - EE);
            atomicAdd(&counts[d], 1);
        }
    } else {
        u16* p0 = n0bf + (size_t)NN * 64;
        for (int i = threadIdx.x; i < (NPAD - NN) * 64; i += 256) p0[i] = 0;
        u16* p1 = nbf + (size_t)NN * 256;
        for (int i = threadIdx.x; i < (NPAD - NN) * 256; i += 256) p1[i] = 0;
    }
}

// ---------------- CSR scan ----------------
__global__ __launch_bounds__(256) void k_scan_block(const int* __restrict__ counts, int* __restrict__ scanned,
                                                    int* __restrict__ bsums, int n) {
    __shared__ int sh[256];
    int i = blockIdx.x * 256 + threadIdx.x;
    int v = (i < n) ? counts[i] : 0;
    sh[threadIdx.x] = v; __syncthreads();
    for (int d = 1; d < 256; d <<= 1) {
        int t = (threadIdx.x >= d) ? sh[threadIdx.x - d] : 0;
        __syncthreads();
        sh[threadIdx.x] += t;
        __syncthreads();
    }
    if (i < n) scanned[i] = sh[threadIdx.x] - v;
    if (threadIdx.x == 255) bsums[blockIdx.x] = sh[255];
}

__global__ __launch_bounds__(256) void k_scan_add2(const int* __restrict__ scanned, const int* __restrict__ bsums,
                                                   int* __restrict__ indptr, int* __restrict__ fill) {
    __shared__ int sh[256];
    int t = threadIdx.x;
    int v = (t < NB_SCAN) ? bsums[t] : 0;
    sh[t] = v; __syncthreads();
    for (int d = 1; d < 256; d <<= 1) {
        int u = (t >= d) ? sh[t - d] : 0;
        __syncthreads();
        sh[t] += u;
        __syncthreads();
    }
    int bix = blockIdx.x;
    int boff = (bix == 0) ? 0 : sh[bix - 1];
    int i = bix * 256 + t;
    if (i < NN) { indptr[i] = scanned[i] + boff; fill[i] = 0; }
    if (i == 0) indptr[NN] = ETOT;
}

__global__ __launch_bounds__(256) void k_fill(const int* __restrict__ ei, const int* __restrict__ indptr,
                                              int* __restrict__ fill, int* __restrict__ esrc) {
    int e = blockIdx.x * 256 + threadIdx.x;
    if (e >= ETOT) return;
    int s, d;
    if (e < EE) { s = ei[e]; d = ei[EE + e]; } else { s = d = e - EE; }
    int pos = atomicAdd(&fill[d], 1);
    esrc[indptr[d] + pos] = s;
}

// ---------------- bf16 MFMA GEMM + fused a_s/a_d epilogue (scores pre-scaled by log2e) ----------------
__global__ __launch_bounds__(256) void k_gemm_mfma(const u16* __restrict__ A,
                                                   const u16* __restrict__ Bt,
                                                   const float* __restrict__ att_s,
                                                   const float* __restrict__ att_d,
                                                   u16* __restrict__ Hbf,
                                                   float* __restrict__ a_s,
                                                   float* __restrict__ a_d,
                                                   int K) {
    __shared__ __align__(16) u16 As[128 * 64];
    __shared__ __align__(16) u16 Bs[128 * 64];
    const int tid = threadIdx.x;
    const int lane = tid & 63;
    const int w = tid >> 6;
    const int wr = w >> 1, wc = w & 1;
    const int row0 = blockIdx.x * BM;
    const int col0 = blockIdx.y * BN;

    f32x4 acc[4][4] = {};

    for (int kt = 0; kt < K; kt += 64) {
#pragma unroll
        for (int i = 0; i < 4; ++i) {
            int u = i * 256 + tid;
            int r = u >> 3, c16 = u & 7;
            int sc = ((c16 ^ (r & 7)) << 3);
            const u16* ga = A + (size_t)(row0 + r) * K + kt + sc;
            u16* la = &As[(size_t)(i * 256 + (w << 6)) * 8];
            __builtin_amdgcn_global_load_lds((const __attribute__((address_space(1))) void*)ga,
                                             (__attribute__((address_space(3))) void*)la, 16, 0, 0);
        }
#pragma unroll
        for (int i = 0; i < 4; ++i) {
            int u = i * 256 + tid;
            int r = u >> 3, c16 = u & 7;
            int sc = ((c16 ^ (r & 7)) << 3);
            const u16* gb = Bt + (size_t)(col0 + r) * K + kt + sc;
            u16* lb = &Bs[(size_t)(i * 256 + (w << 6)) * 8];
            __builtin_amdgcn_global_load_lds((const __attribute__((address_space(1))) void*)gb,
                                             (__attribute__((address_space(3))) void*)lb, 16, 0, 0);
        }
        __syncthreads();
#pragma unroll
        for (int ks = 0; ks < 2; ++ks) {
            s16x8 af[4], bfr[4];
#pragma unroll
            for (int m = 0; m < 4; ++m) {
                int ra = wr * 64 + m * 16 + (lane & 15);
                int c16 = ks * 4 + (lane >> 4);
                int off = ra * 64 + ((c16 ^ (ra & 7)) << 3);
                af[m] = *reinterpret_cast<const s16x8*>(&As[off]);
            }
#pragma unroll
            for (int n = 0; n < 4; ++n) {
                int rb = wc * 64 + n * 16 + (lane & 15);
                int c16 = ks * 4 + (lane >> 4);
                int off = rb * 64 + ((c16 ^ (rb & 7)) << 3);
                bfr[n] = *reinterpret_cast<const s16x8*>(&Bs[off]);
            }
#pragma unroll
            for (int m = 0; m < 4; ++m)
#pragma unroll
                for (int n = 0; n < 4; ++n)
                    acc[m][n] = __builtin_amdgcn_mfma_f32_16x16x32_bf16(af[m], bfr[n], acc[m][n], 0, 0, 0);
        }
        __syncthreads();
    }

    const int head = (blockIdx.y << 1) + wc;
    float asv[4], adv[4];
#pragma unroll
    for (int n = 0; n < 4; ++n) {
        asv[n] = att_s[head * 64 + n * 16 + (lane & 15)] * LOG2E;
        adv[n] = att_d[head * 64 + n * 16 + (lane & 15)] * LOG2E;
    }
#pragma unroll
    for (int m = 0; m < 4; ++m) {
        int growb = row0 + wr * 64 + m * 16 + (lane >> 4) * 4;
#pragma unroll
        for (int j = 0; j < 4; ++j) {
            int grow = growb + j;
            u16* orow = Hbf + (size_t)grow * 256 + col0 + wc * 64 + (lane & 15);
            float vs = 0.f, vd = 0.f;
#pragma unroll
            for (int n = 0; n < 4; ++n) {
                float v = acc[m][n][j];
                orow[n * 16] = f2bf(v);
                vs += v * asv[n];
                vd += v * adv[n];
            }
            vs += __shfl_xor(vs, 1); vd += __shfl_xor(vd, 1);
            vs += __shfl_xor(vs, 2); vd += __shfl_xor(vd, 2);
            vs += __shfl_xor(vs, 4); vd += __shfl_xor(vd, 4);
            vs += __shfl_xor(vs, 8); vd += __shfl_xor(vd, 8);
            if ((lane & 15) == 0) {
                a_s[grow * 4 + head] = vs;
                a_d[grow * 4 + head] = vd;
            }
        }
    }
}

// ---------------- two-node-per-wave online-softmax aggregate + fused pool ----------------
// block = 1024 thr = 16 waves = 32 nodes. Each half-wave (32 lanes) owns one node:
// phase A: 8 edge-slots x 4 heads per half; phase B: ushort8 half-wave row loads (8 ch/lane).
__global__ __launch_bounds__(1024) void k_agg(const u16* __restrict__ Hbf, const float* __restrict__ a_s,
                                              const float* __restrict__ a_d, const int* __restrict__ indptr,
                                              const int* __restrict__ esrc, const float* __restrict__ bias,
                                              const int* __restrict__ batch, u16* __restrict__ outbf,
                                              int* __restrict__ gbuf, int poolOff) {
    __shared__ int lpool[2][256];
    __shared__ int sb[32];
    if (threadIdx.x < 512) lpool[threadIdx.x >> 8][threadIdx.x & 255] = 0;
    const int nodeBase = blockIdx.x * 32;
    if (threadIdx.x < 32) {
        int nn = nodeBase + threadIdx.x;
        sb[threadIdx.x] = (nn < NN) ? batch[nn] : -1;
    }
    __syncthreads();

    const int wv = threadIdx.x >> 6;
    const int lane = threadIdx.x & 63;
    const int half = lane >> 5;
    const int l5 = lane & 31;
    const int nslot = wv * 2 + half;
    const int wid = nodeBase + nslot;
    const int h = l5 >> 3;       // head (phase A) == channel head (phase B: channels l5*8..+7)
    const int eidx = l5 & 7;
    const bool active = wid < NN;

    if (active) {
        int beg = indptr[wid];
        int dcount = indptr[wid + 1] - beg;
        int dmax = max(dcount, __shfl_xor(dcount, 32));   // wave loop bound
        float ad = a_d[wid * 4 + h];
        float mx = -3.0e38f, ssum = 0.f;
        float a0 = 0.f, a1 = 0.f, a2 = 0.f, a3 = 0.f, a4 = 0.f, a5 = 0.f, a6 = 0.f, a7 = 0.f;

        for (int cb = 0; cb < dmax; cb += 8) {
            int cnt = min(8, dcount - cb);               // per-half; may be <= 0
            // ---- phase A: 8 edges x 4 heads per half-wave ----
            int s = (eidx < cnt) ? esrc[beg + cb + eidx] : 0;
            float el = (eidx < cnt) ? a_s[s * 4 + h] + ad : -3.0e38f;
            el = fmaxf(el, 0.2f * el);
            float cm = el;
            cm = fmaxf(cm, __shfl_xor(cm, 1));
            cm = fmaxf(cm, __shfl_xor(cm, 2));
            cm = fmaxf(cm, __shfl_xor(cm, 4));
            float nm = fmaxf(mx, cm);
            if (__any(nm > mx)) {
                float corr = exp2f(mx - nm);
                ssum *= corr;
                a0 *= corr; a1 *= corr; a2 *= corr; a3 *= corr;
                a4 *= corr; a5 *= corr; a6 *= corr; a7 *= corr;
            }
            mx = nm;
            float p = exp2f(el - mx);                    // invalid lanes -> 0
            float cs = p;
            cs += __shfl_xor(cs, 1);
            cs += __shfl_xor(cs, 2);
            cs += __shfl_xor(cs, 4);
            ssum += cs;
            // ---- phase B: half-wave row loads, 2-wide ----
            int hb = half << 5;
            int k = 0;
            for (; k + 2 <= cnt; k += 2) {
                int sk0 = __shfl(s, hb | k);
                int sk1 = __shfl(s, hb | (k + 1));
                float p0 = __shfl(p, hb | (h << 3) | k);
                float p1 = __shfl(p, hb | (h << 3) | (k + 1));
                const s16x8 h0 = *reinterpret_cast<const s16x8*>(Hbf + (size_t)sk0 * 256 + l5 * 8);
                const s16x8 h1 = *reinterpret_cast<const s16x8*>(Hbf + (size_t)sk1 * 256 + l5 * 8);
                a0 += p0 * bf2f((u16)h0[0]) + p1 * bf2f((u16)h1[0]);
                a1 += p0 * bf2f((u16)h0[1]) + p1 * bf2f((u16)h1[1]);
                a2 += p0 * bf2f((u16)h0[2]) + p1 * bf2f((u16)h1[2]);
                a3 += p0 * bf2f((u16)h0[3]) + p1 * bf2f((u16)h1[3]);
                a4 += p0 * bf2f((u16)h0[4]) + p1 * bf2f((u16)h1[4]);
                a5 += p0 * bf2f((u16)h0[5]) + p1 * bf2f((u16)h1[5]);
                a6 += p0 * bf2f((u16)h0[6]) + p1 * bf2f((u16)h1[6]);
                a7 += p0 * bf2f((u16)h0[7]) + p1 * bf2f((u16)h1[7]);
            }
            if (k < cnt) {
                int sk0 = __shfl(s, hb | k);
                float p0 = __shfl(p, hb | (h << 3) | k);
                const s16x8 h0 = *reinterpret_cast<const s16x8*>(Hbf + (size_t)sk0 * 256 + l5 * 8);
                a0 += p0 * bf2f((u16)h0[0]);
                a1 += p0 * bf2f((u16)h0[1]);
                a2 += p0 * bf2f((u16)h0[2]);
                a3 += p0 * bf2f((u16)h0[3]);
                a4 += p0 * bf2f((u16)h0[4]);
                a5 += p0 * bf2f((u16)h0[5]);
                a6 += p0 * bf2f((u16)h0[6]);
                a7 += p0 * bf2f((u16)h0[7]);
            }
        }

        float inv = 1.0f / ssum;
        const float4 bv0 = *reinterpret_cast<const float4*>(bias + l5 * 8);
        const float4 bv1 = *reinterpret_cast<const float4*>(bias + l5 * 8 + 4);
        float o0 = fmaxf(a0 * inv + bv0.x, 0.f);
        float o1 = fmaxf(a1 * inv + bv0.y, 0.f);
        float o2 = fmaxf(a2 * inv + bv0.z, 0.f);
        float o3 = fmaxf(a3 * inv + bv0.w, 0.f);
        float o4 = fmaxf(a4 * inv + bv1.x, 0.f);
        float o5 = fmaxf(a5 * inv + bv1.y, 0.f);
        float o6 = fmaxf(a6 * inv + bv1.z, 0.f);
        float o7 = fmaxf(a7 * inv + bv1.w, 0.f);
        s16x8 ob;
        ob[0] = (short)f2bf(o0); ob[1] = (short)f2bf(o1); ob[2] = (short)f2bf(o2); ob[3] = (short)f2bf(o3);
        ob[4] = (short)f2bf(o4); ob[5] = (short)f2bf(o5); ob[6] = (short)f2bf(o6); ob[7] = (short)f2bf(o7);
        *reinterpret_cast<s16x8*>(outbf + (size_t)wid * 256 + l5 * 8) = ob;

        // fused pool (LDS dedup over 2 leading graphs, direct atomic fallback)
        int g = sb[nslot];
        int slot = g - sb[0];
        int c8 = l5 * 8;
        if (slot < 2) {
            atomicMax(&lpool[slot][c8],     __float_as_int(o0));
            atomicMax(&lpool[slot][c8 + 1], __float_as_int(o1));
            atomicMax(&lpool[slot][c8 + 2], __float_as_int(o2));
            atomicMax(&lpool[slot][c8 + 3], __float_as_int(o3));
            atomicMax(&lpool[slot][c8 + 4], __float_as_int(o4));
            atomicMax(&lpool[slot][c8 + 5], __float_as_int(o5));
            atomicMax(&lpool[slot][c8 + 6], __float_as_int(o6));
            atomicMax(&lpool[slot][c8 + 7], __float_as_int(o7));
        } else {
            int* cell = &gbuf[g * GCOLS + poolOff + c8];
            atomicMax(cell,     __float_as_int(o0));
            atomicMax(cell + 1, __float_as_int(o1));
            atomicMax(cell + 2, __float_as_int(o2));
            atomicMax(cell + 3, __float_as_int(o3));
            atomicMax(cell + 4, __float_as_int(o4));
            atomicMax(cell + 5, __float_as_int(o5));
            atomicMax(cell + 6, __float_as_int(o6));
            atomicMax(cell + 7, __float_as_int(o7));
        }
    }
    __syncthreads();
    if (threadIdx.x < 512) {
        int slot = threadIdx.x >> 8, c = threadIdx.x & 255;
        int v = lpool[slot][c];
        if (v != 0 && sb[0] >= 0)
            atomicMax(&gbuf[(sb[0] + slot) * GCOLS + poolOff + c], v);
    }
}

// ---------------- fused head: 1024 thr, k-split 4-ways ----------------
__global__ __launch_bounds__(1024) void k_head(const int* __restrict__ gbuf,
                                               const float* __restrict__ aggW, const float* __restrict__ aggb,
                                               const float* __restrict__ muW, const float* __restrict__ mub,
                                               const float* __restrict__ varW, const float* __restrict__ varb,
                                               float* __restrict__ out) {
    __shared__ float part[4][256];
    __shared__ float lat[LATD];
    int gi = blockIdx.x;
    int j = threadIdx.x & 255, ks = threadIdx.x >> 8;
    const float* g = (const float*)gbuf + (size_t)gi * GCOLS;
    float acc = 0.f;
    int k0 = ks * 208;
    for (int k = k0; k < k0 + 208; ++k) acc += g[k] * aggW[k * 256 + j];
    part[ks][j] = acc;
    __syncthreads();
    if (ks == 0) lat[j] = part[0][j] + part[1][j] + part[2][j] + part[3][j] + aggb[j];
    __syncthreads();
    const float* W = (ks < 2) ? muW : varW;
    int kb = (ks & 1) * 128;
    float am = 0.f;
    for (int k = kb; k < kb + 128; ++k) am += lat[k] * W[k * 256 + j];
    part[ks][j] = am;
    __syncthreads();
    if (ks == 0) out[(size_t)gi * 256 + j] = part[0][j] + part[1][j] + mub[j];
    else if (ks == 1) out[(size_t)GG * 256 + (size_t)gi * 256 + j] = part[2][j] + part[3][j] + varb[j];
}

extern "C" void kernel_launch(void* const* d_in, const int* in_sizes, int n_in,
                              void* d_out, int out_size, void* d_ws, size_t ws_size,
                              hipStream_t stream) {
    const float* bf   = (const float*)d_in[0];
    const int*   ei   = (const int*)d_in[1];
    const int*   batch= (const int*)d_in[2];
    const float* bf_W = (const float*)d_in[3];
    const float* bf_b = (const float*)d_in[4];
    const float* W1   = (const float*)d_in[5];
    const float* as1  = (const float*)d_in[6];
    const float* ad1  = (const float*)d_in[7];
    const float* b1   = (const float*)d_in[8];
    const float* W2   = (const float*)d_in[9];
    const float* as2  = (const float*)d_in[10];
    const float* ad2  = (const float*)d_in[11];
    const float* b2   = (const float*)d_in[12];
    const float* W3   = (const float*)d_in[13];
    const float* as3  = (const float*)d_in[14];
    const float* ad3  = (const float*)d_in[15];
    const float* b3   = (const float*)d_in[16];
    const float* aggW = (const float*)d_in[17];
    const float* aggb = (const float*)d_in[18];
    const float* muW  = (const float*)d_in[19];
    const float* mub  = (const float*)d_in[20];
    const float* varW = (const float*)d_in[21];
    const float* varb = (const float*)d_in[22];
    float* out = (float*)d_out;

    size_t off = 0;
    auto alloc = [&](size_t bytes) -> char* {
        char* p = (char*)d_ws + off;
        off += (bytes + 255) & ~(size_t)255;
        return p;
    };
    int*   counts  = (int*)alloc((size_t)(NN + GG * GCOLS) * 4);
    int*   gbuf    = counts + NN;
    u16*   Hbf     = (u16*)alloc((size_t)NPAD * 256 * 2);
    u16*   n0bf    = (u16*)alloc((size_t)NPAD * 64 * 2);
    u16*   nbf     = (u16*)alloc((size_t)NPAD * 256 * 2);
    float* a_s     = (float*)alloc((size_t)NPAD * 4 * 4);
    float* a_d     = (float*)alloc((size_t)NPAD * 4 * 4);
    int*   scanned = (int*)alloc((size_t)NN * 4);
    int*   bsums   = (int*)alloc(256 * 4);
    int*   indptr  = (int*)alloc((size_t)(NN + 1) * 4);
    int*   fill    = (int*)alloc((size_t)NN * 4);
    int*   esrc    = (int*)alloc((size_t)(ETOT + 16) * 4);
    u16*   Wt1     = (u16*)alloc((size_t)256 * 64 * 2);
    u16*   Wt2     = (u16*)alloc((size_t)256 * 256 * 2);
    u16*   Wt3     = (u16*)alloc((size_t)256 * 256 * 2);

    hipMemsetAsync(counts, 0, (size_t)(NN + GG * GCOLS) * 4, stream);

    k_prep<<<2336, 256, 0, stream>>>(W1, W2, W3, Wt1, Wt2, Wt3,
                                     bf, bf_W, bf_b, batch, n0bf, gbuf,
                                     ei, counts, nbf);

    k_scan_block<<<NB_SCAN, 256, 0, stream>>>(counts, scanned, bsums, NN);
    k_scan_add2<<<NB_SCAN, 256, 0, stream>>>(scanned, bsums, indptr, fill);
    k_fill<<<(ETOT + 255) / 256, 256, 0, stream>>>(ei, indptr, fill, esrc);

    dim3 ggrid(NPAD / BM, 256 / BN);     // (391, 2)
    const int AB = (NN + 31) / 32;       // 1563

    // ---- layer 1 (K=64) ----
    k_gemm_mfma<<<ggrid, 256, 0, stream>>>(n0bf, Wt1, as1, ad1, Hbf, a_s, a_d, 64);
    k_agg<<<AB, 1024, 0, stream>>>(Hbf, a_s, a_d, indptr, esrc, b1, batch, nbf, gbuf, 64);

    // ---- layer 2 (K=256) ----
    k_gemm_mfma<<<ggrid, 256, 0, stream>>>(nbf, Wt2, as2, ad2, Hbf, a_s, a_d, 256);
    k_agg<<<AB, 1024, 0, stream>>>(Hbf, a_s, a_d, indptr, esrc, b2, batch, nbf, gbuf, 320);

    // ---- layer 3 (K=256) ----
    k_gemm_mfma<<<ggrid, 256, 0, stream>>>(nbf, Wt3, as3, ad3, Hbf, a_s, a_d, 256);
    k_agg<<<AB, 1024, 0, stream>>>(Hbf, a_s, a_d, indptr, esrc, b3, batch, nbf, gbuf, 576);

    // ---- head ----
    k_head<<<GG, 1024, 0, stream>>>(gbuf, aggW, aggb, muW, mub, varW, varb, out);
}

// Round 11
// 257.621 us; speedup vs baseline: 1.2656x; 1.0012x over previous
//
#include <hip/hip_runtime.h>
#include <hip/hip_bf16.h>

#define NN 50000
#define NPAD 50048              // 391 * 128
#define EE 300000
#define ETOT (EE + NN)          // 350000 edges incl self-loops
#define GG 64
#define GCOLS 832               // 64 + 3*256
#define LATD 256
#define BM 128
#define BN 128
#define NB_SCAN 196             // (NN+255)/256
#define LOG2E 1.4426950408889634f
#define ZWORDS (NN + GG * GCOLS)   // 103248 dwords zeroed (counts + gbuf)

typedef unsigned short u16;
typedef short s16x8 __attribute__((ext_vector_type(8)));
typedef float f32x4 __attribute__((ext_vector_type(4)));

__device__ __forceinline__ u16 f2bf(float f) {
    union { float f; unsigned u; } v; v.f = f;
    unsigned r = v.u + 0x7FFFu + ((v.u >> 16) & 1u);
    return (u16)(r >> 16);
}
__device__ __forceinline__ float bf2f(u16 u) {
    union { unsigned u; float f; } v; v.u = ((unsigned)u) << 16;
    return v.f;
}

// ---------------- fast zero of counts+gbuf (replaces pathological runtime memset) ----------------
__global__ __launch_bounds__(256) void k_zero(int4* __restrict__ p) {
    int i = blockIdx.x * 256 + threadIdx.x;           // int4 index
    if (i < ZWORDS / 4) p[i] = make_int4(0, 0, 0, 0);
}

// ---------------- prep: weight transposes | n0+pool | edge count | pad zero ----------------
__global__ __launch_bounds__(256) void k_prep(const float* __restrict__ W1, const float* __restrict__ W2,
                                              const float* __restrict__ W3, u16* __restrict__ Wt1,
                                              u16* __restrict__ Wt2, u16* __restrict__ Wt3,
                                              const float* __restrict__ bf, const float* __restrict__ Wb,
                                              const float* __restrict__ bb, const int* __restrict__ batch,
                                              u16* __restrict__ n0bf, int* __restrict__ gbuf,
                                              const int* __restrict__ ei, int* __restrict__ counts,
                                              u16* __restrict__ nbf) {
    int b = blockIdx.x;
    if (b < 576) {
        int idx = b * 256 + threadIdx.x;
        if (idx < 16384) {
            int n = idx >> 6, k = idx & 63;
            Wt1[idx] = f2bf(W1[k * 256 + n]);
        } else if (idx < 81920) {
            int t = idx - 16384; int n = t >> 8, k = t & 255;
            Wt2[t] = f2bf(W2[k * 256 + n]);
        } else {
            int t = idx - 81920; int n = t >> 8, k = t & 255;
            Wt3[t] = f2bf(W3[k * 256 + n]);
        }
    } else if (b < 967) {
        int c = threadIdx.x & 63;
        int sub = threadIdx.x >> 6;
        int base = (b - 576) * 128;
        int end = min(base + 128, NN);
        float w0 = Wb[c], w1 = Wb[64 + c], w2 = Wb[128 + c], w3 = Wb[192 + c], w4 = Wb[256 + c], bb_ = bb[c];
        float mx = 0.f;
        int curg = -1;
        for (int n = base + sub; n < end; n += 4) {
            const float* r = bf + (size_t)n * 5;
            float v = bb_ + r[0] * w0 + r[1] * w1 + r[2] * w2 + r[3] * w3 + r[4] * w4;
            v = fmaxf(v, 0.f);
            n0bf[(size_t)n * 64 + c] = f2bf(v);
            int g = batch[n];
            if (g != curg) {
                if (curg >= 0) atomicMax(&gbuf[curg * GCOLS + c], __float_as_int(mx));
                mx = 0.f; curg = g;
            }
            mx = fmaxf(mx, v);
        }
        if (curg >= 0) atomicMax(&gbuf[curg * GCOLS + c], __float_as_int(mx));
    } else if (b < 2335) {
        int e = (b - 967) * 256 + threadIdx.x;
        if (e < ETOT) {
            int d = (e < EE) ? ei[EE + e] : (e - EE);
            atomicAdd(&counts[d], 1);
        }
    } else {
        u16* p0 = n0bf + (size_t)NN * 64;
        for (int i = threadIdx.x; i < (NPAD - NN) * 64; i += 256) p0[i] = 0;
        u16* p1 = nbf + (size_t)NN * 256;
        for (int i = threadIdx.x; i < (NPAD - NN) * 256; i += 256) p1[i] = 0;
    }
}

// ---------------- CSR scan ----------------
__global__ __launch_bounds__(256) void k_scan_block(const int* __restrict__ counts, int* __restrict__ scanned,
                                                    int* __restrict__ bsums, int n) {
    __shared__ int sh[256];
    int i = blockIdx.x * 256 + threadIdx.x;
    int v = (i < n) ? counts[i] : 0;
    sh[threadIdx.x] = v; __syncthreads();
    for (int d = 1; d < 256; d <<= 1) {
        int t = (threadIdx.x >= d) ? sh[threadIdx.x - d] : 0;
        __syncthreads();
        sh[threadIdx.x] += t;
        __syncthreads();
    }
    if (i < n) scanned[i] = sh[threadIdx.x] - v;
    if (threadIdx.x == 255) bsums[blockIdx.x] = sh[255];
}

__global__ __launch_bounds__(256) void k_scan_add2(const int* __restrict__ scanned, const int* __restrict__ bsums,
                                                   int* __restrict__ indptr, int* __restrict__ fill) {
    __shared__ int sh[256];
    int t = threadIdx.x;
    int v = (t < NB_SCAN) ? bsums[t] : 0;
    sh[t] = v; __syncthreads();
    for (int d = 1; d < 256; d <<= 1) {
        int u = (t >= d) ? sh[t - d] : 0;
        __syncthreads();
        sh[t] += u;
        __syncthreads();
    }
    int bix = blockIdx.x;
    int boff = (bix == 0) ? 0 : sh[bix - 1];
    int i = bix * 256 + t;
    if (i < NN) { indptr[i] = scanned[i] + boff; fill[i] = 0; }
    if (i == 0) indptr[NN] = ETOT;
}

__global__ __launch_bounds__(256) void k_fill(const int* __restrict__ ei, const int* __restrict__ indptr,
                                              int* __restrict__ fill, int* __restrict__ esrc) {
    int e = blockIdx.x * 256 + threadIdx.x;
    if (e >= ETOT) return;
    int s, d;
    if (e < EE) { s = ei[e]; d = ei[EE + e]; } else { s = d = e - EE; }
    int pos = atomicAdd(&fill[d], 1);
    esrc[indptr[d] + pos] = s;
}

// ---------------- bf16 MFMA GEMM + fused a_s/a_d epilogue (scores pre-scaled by log2e) ----------------
__global__ __launch_bounds__(256) void k_gemm_mfma(const u16* __restrict__ A,
                                                   const u16* __restrict__ Bt,
                                                   const float* __restrict__ att_s,
                                                   const float* __restrict__ att_d,
                                                   u16* __restrict__ Hbf,
                                                   float* __restrict__ a_s,
                                                   float* __restrict__ a_d,
                                                   int K) {
    __shared__ __align__(16) u16 As[128 * 64];
    __shared__ __align__(16) u16 Bs[128 * 64];
    const int tid = threadIdx.x;
    const int lane = tid & 63;
    const int w = tid >> 6;
    const int wr = w >> 1, wc = w & 1;
    const int row0 = blockIdx.x * BM;
    const int col0 = blockIdx.y * BN;

    f32x4 acc[4][4] = {};

    for (int kt = 0; kt < K; kt += 64) {
#pragma unroll
        for (int i = 0; i < 4; ++i) {
            int u = i * 256 + tid;
            int r = u >> 3, c16 = u & 7;
            int sc = ((c16 ^ (r & 7)) << 3);
            const u16* ga = A + (size_t)(row0 + r) * K + kt + sc;
            u16* la = &As[(size_t)(i * 256 + (w << 6)) * 8];
            __builtin_amdgcn_global_load_lds((const __attribute__((address_space(1))) void*)ga,
                                             (__attribute__((address_space(3))) void*)la, 16, 0, 0);
        }
#pragma unroll
        for (int i = 0; i < 4; ++i) {
            int u = i * 256 + tid;
            int r = u >> 3, c16 = u & 7;
            int sc = ((c16 ^ (r & 7)) << 3);
            const u16* gb = Bt + (size_t)(col0 + r) * K + kt + sc;
            u16* lb = &Bs[(size_t)(i * 256 + (w << 6)) * 8];
            __builtin_amdgcn_global_load_lds((const __attribute__((address_space(1))) void*)gb,
                                             (__attribute__((address_space(3))) void*)lb, 16, 0, 0);
        }
        __syncthreads();
#pragma unroll
        for (int ks = 0; ks < 2; ++ks) {
            s16x8 af[4], bfr[4];
#pragma unroll
            for (int m = 0; m < 4; ++m) {
                int ra = wr * 64 + m * 16 + (lane & 15);
                int c16 = ks * 4 + (lane >> 4);
                int off = ra * 64 + ((c16 ^ (ra & 7)) << 3);
                af[m] = *reinterpret_cast<const s16x8*>(&As[off]);
            }
#pragma unroll
            for (int n = 0; n < 4; ++n) {
                int rb = wc * 64 + n * 16 + (lane & 15);
                int c16 = ks * 4 + (lane >> 4);
                int off = rb * 64 + ((c16 ^ (rb & 7)) << 3);
                bfr[n] = *reinterpret_cast<const s16x8*>(&Bs[off]);
            }
#pragma unroll
            for (int m = 0; m < 4; ++m)
#pragma unroll
                for (int n = 0; n < 4; ++n)
                    acc[m][n] = __builtin_amdgcn_mfma_f32_16x16x32_bf16(af[m], bfr[n], acc[m][n], 0, 0, 0);
        }
        __syncthreads();
    }

    const int head = (blockIdx.y << 1) + wc;
    float asv[4], adv[4];
#pragma unroll
    for (int n = 0; n < 4; ++n) {
        asv[n] = att_s[head * 64 + n * 16 + (lane & 15)] * LOG2E;
        adv[n] = att_d[head * 64 + n * 16 + (lane & 15)] * LOG2E;
    }
#pragma unroll
    for (int m = 0; m < 4; ++m) {
        int growb = row0 + wr * 64 + m * 16 + (lane >> 4) * 4;
#pragma unroll
        for (int j = 0; j < 4; ++j) {
            int grow = growb + j;
            u16* orow = Hbf + (size_t)grow * 256 + col0 + wc * 64 + (lane & 15);
            float vs = 0.f, vd = 0.f;
#pragma unroll
            for (int n = 0; n < 4; ++n) {
                float v = acc[m][n][j];
                orow[n * 16] = f2bf(v);
                vs += v * asv[n];
                vd += v * adv[n];
            }
            vs += __shfl_xor(vs, 1); vd += __shfl_xor(vd, 1);
            vs += __shfl_xor(vs, 2); vd += __shfl_xor(vd, 2);
            vs += __shfl_xor(vs, 4); vd += __shfl_xor(vd, 4);
            vs += __shfl_xor(vs, 8); vd += __shfl_xor(vd, 8);
            if ((lane & 15) == 0) {
                a_s[grow * 4 + head] = vs;
                a_d[grow * 4 + head] = vd;
            }
        }
    }
}

// ---------------- two-node-per-wave online-softmax aggregate + fused pool ----------------
__global__ __launch_bounds__(1024) void k_agg(const u16* __restrict__ Hbf, const float* __restrict__ a_s,
                                              const float* __restrict__ a_d, const int* __restrict__ indptr,
                                              const int* __restrict__ esrc, const float* __restrict__ bias,
                                              const int* __restrict__ batch, u16* __restrict__ outbf,
                                              int* __restrict__ gbuf, int poolOff) {
    __shared__ int lpool[2][256];
    __shared__ int sb[32];
    if (threadIdx.x < 512) lpool[threadIdx.x >> 8][threadIdx.x & 255] = 0;
    const int nodeBase = blockIdx.x * 32;
    if (threadIdx.x < 32) {
        int nn = nodeBase + threadIdx.x;
        sb[threadIdx.x] = (nn < NN) ? batch[nn] : -1;
    }
    __syncthreads();

    const int wv = threadIdx.x >> 6;
    const int lane = threadIdx.x & 63;
    const int half = lane >> 5;
    const int l5 = lane & 31;
    const int nslot = wv * 2 + half;
    const int wid = nodeBase + nslot;
    const int h = l5 >> 3;
    const int eidx = l5 & 7;
    const bool active = wid < NN;

    if (active) {
        int beg = indptr[wid];
        int dcount = indptr[wid + 1] - beg;
        int dmax = max(dcount, __shfl_xor(dcount, 32));
        float ad = a_d[wid * 4 + h];
        float mx = -3.0e38f, ssum = 0.f;
        float a0 = 0.f, a1 = 0.f, a2 = 0.f, a3 = 0.f, a4 = 0.f, a5 = 0.f, a6 = 0.f, a7 = 0.f;

        for (int cb = 0; cb < dmax; cb += 8) {
            int cnt = min(8, dcount - cb);
            int s = (eidx < cnt) ? esrc[beg + cb + eidx] : 0;
            float el = (eidx < cnt) ? a_s[s * 4 + h] + ad : -3.0e38f;
            el = fmaxf(el, 0.2f * el);
            float cm = el;
            cm = fmaxf(cm, __shfl_xor(cm, 1));
            cm = fmaxf(cm, __shfl_xor(cm, 2));
            cm = fmaxf(cm, __shfl_xor(cm, 4));
            float nm = fmaxf(mx, cm);
            if (__any(nm > mx)) {
                float corr = exp2f(mx - nm);
                ssum *= corr;
                a0 *= corr; a1 *= corr; a2 *= corr; a3 *= corr;
                a4 *= corr; a5 *= corr; a6 *= corr; a7 *= corr;
            }
            mx = nm;
            float p = exp2f(el - mx);
            float cs = p;
            cs += __shfl_xor(cs, 1);
            cs += __shfl_xor(cs, 2);
            cs += __shfl_xor(cs, 4);
            ssum += cs;
            int hb = half << 5;
            int k = 0;
            for (; k + 2 <= cnt; k += 2) {
                int sk0 = __shfl(s, hb | k);
                int sk1 = __shfl(s, hb | (k + 1));
                float p0 = __shfl(p, hb | (h << 3) | k);
                float p1 = __shfl(p, hb | (h << 3) | (k + 1));
                const s16x8 h0 = *reinterpret_cast<const s16x8*>(Hbf + (size_t)sk0 * 256 + l5 * 8);
                const s16x8 h1 = *reinterpret_cast<const s16x8*>(Hbf + (size_t)sk1 * 256 + l5 * 8);
                a0 += p0 * bf2f((u16)h0[0]) + p1 * bf2f((u16)h1[0]);
                a1 += p0 * bf2f((u16)h0[1]) + p1 * bf2f((u16)h1[1]);
                a2 += p0 * bf2f((u16)h0[2]) + p1 * bf2f((u16)h1[2]);
                a3 += p0 * bf2f((u16)h0[3]) + p1 * bf2f((u16)h1[3]);
                a4 += p0 * bf2f((u16)h0[4]) + p1 * bf2f((u16)h1[4]);
                a5 += p0 * bf2f((u16)h0[5]) + p1 * bf2f((u16)h1[5]);
                a6 += p0 * bf2f((u16)h0[6]) + p1 * bf2f((u16)h1[6]);
                a7 += p0 * bf2f((u16)h0[7]) + p1 * bf2f((u16)h1[7]);
            }
            if (k < cnt) {
                int sk0 = __shfl(s, hb | k);
                float p0 = __shfl(p, hb | (h << 3) | k);
                const s16x8 h0 = *reinterpret_cast<const s16x8*>(Hbf + (size_t)sk0 * 256 + l5 * 8);
                a0 += p0 * bf2f((u16)h0[0]);
                a1 += p0 * bf2f((u16)h0[1]);
                a2 += p0 * bf2f((u16)h0[2]);
                a3 += p0 * bf2f((u16)h0[3]);
                a4 += p0 * bf2f((u16)h0[4]);
                a5 += p0 * bf2f((u16)h0[5]);
                a6 += p0 * bf2f((u16)h0[6]);
                a7 += p0 * bf2f((u16)h0[7]);
            }
        }

        float inv = 1.0f / ssum;
        const float4 bv0 = *reinterpret_cast<const float4*>(bias + l5 * 8);
        const float4 bv1 = *reinterpret_cast<const float4*>(bias + l5 * 8 + 4);
        float o0 = fmaxf(a0 * inv + bv0.x, 0.f);
        float o1 = fmaxf(a1 * inv + bv0.y, 0.f);
        float o2 = fmaxf(a2 * inv + bv0.z, 0.f);
        float o3 = fmaxf(a3 * inv + bv0.w, 0.f);
        float o4 = fmaxf(a4 * inv + bv1.x, 0.f);
        float o5 = fmaxf(a5 * inv + bv1.y, 0.f);
        float o6 = fmaxf(a6 * inv + bv1.z, 0.f);
        float o7 = fmaxf(a7 * inv + bv1.w, 0.f);
        s16x8 ob;
        ob[0] = (short)f2bf(o0); ob[1] = (short)f2bf(o1); ob[2] = (short)f2bf(o2); ob[3] = (short)f2bf(o3);
        ob[4] = (short)f2bf(o4); ob[5] = (short)f2bf(o5); ob[6] = (short)f2bf(o6); ob[7] = (short)f2bf(o7);
        *reinterpret_cast<s16x8*>(outbf + (size_t)wid * 256 + l5 * 8) = ob;

        int g = sb[nslot];
        int slot = g - sb[0];
        int c8 = l5 * 8;
        if (slot < 2) {
            atomicMax(&lpool[slot][c8],     __float_as_int(o0));
            atomicMax(&lpool[slot][c8 + 1], __float_as_int(o1));
            atomicMax(&lpool[slot][c8 + 2], __float_as_int(o2));
            atomicMax(&lpool[slot][c8 + 3], __float_as_int(o3));
            atomicMax(&lpool[slot][c8 + 4], __float_as_int(o4));
            atomicMax(&lpool[slot][c8 + 5], __float_as_int(o5));
            atomicMax(&lpool[slot][c8 + 6], __float_as_int(o6));
            atomicMax(&lpool[slot][c8 + 7], __float_as_int(o7));
        } else {
            int* cell = &gbuf[g * GCOLS + poolOff + c8];
            atomicMax(cell,     __float_as_int(o0));
            atomicMax(cell + 1, __float_as_int(o1));
            atomicMax(cell + 2, __float_as_int(o2));
            atomicMax(cell + 3, __float_as_int(o3));
            atomicMax(cell + 4, __float_as_int(o4));
            atomicMax(cell + 5, __float_as_int(o5));
            atomicMax(cell + 6, __float_as_int(o6));
            atomicMax(cell + 7, __float_as_int(o7));
        }
    }
    __syncthreads();
    if (threadIdx.x < 512) {
        int slot = threadIdx.x >> 8, c = threadIdx.x & 255;
        int v = lpool[slot][c];
        if (v != 0 && sb[0] >= 0)
            atomicMax(&gbuf[(sb[0] + slot) * GCOLS + poolOff + c], v);
    }
}

// ---------------- fused head: 1024 thr, k-split 4-ways ----------------
__global__ __launch_bounds__(1024) void k_head(const int* __restrict__ gbuf,
                                               const float* __restrict__ aggW, const float* __restrict__ aggb,
                                               const float* __restrict__ muW, const float* __restrict__ mub,
                                               const float* __restrict__ varW, const float* __restrict__ varb,
                                               float* __restrict__ out) {
    __shared__ float part[4][256];
    __shared__ float lat[LATD];
    int gi = blockIdx.x;
    int j = threadIdx.x & 255, ks = threadIdx.x >> 8;
    const float* g = (const float*)gbuf + (size_t)gi * GCOLS;
    float acc = 0.f;
    int k0 = ks * 208;
    for (int k = k0; k < k0 + 208; ++k) acc += g[k] * aggW[k * 256 + j];
    part[ks][j] = acc;
    __syncthreads();
    if (ks == 0) lat[j] = part[0][j] + part[1][j] + part[2][j] + part[3][j] + aggb[j];
    __syncthreads();
    const float* W = (ks < 2) ? muW : varW;
    int kb = (ks & 1) * 128;
    float am = 0.f;
    for (int k = kb; k < kb + 128; ++k) am += lat[k] * W[k * 256 + j];
    part[ks][j] = am;
    __syncthreads();
    if (ks == 0) out[(size_t)gi * 256 + j] = part[0][j] + part[1][j] + mub[j];
    else if (ks == 1) out[(size_t)GG * 256 + (size_t)gi * 256 + j] = part[2][j] + part[3][j] + varb[j];
}

extern "C" void kernel_launch(void* const* d_in, const int* in_sizes, int n_in,
                              void* d_out, int out_size, void* d_ws, size_t ws_size,
                              hipStream_t stream) {
    const float* bf   = (const float*)d_in[0];
    const int*   ei   = (const int*)d_in[1];
    const int*   batch= (const int*)d_in[2];
    const float* bf_W = (const float*)d_in[3];
    const float* bf_b = (const float*)d_in[4];
    const float* W1   = (const float*)d_in[5];
    const float* as1  = (const float*)d_in[6];
    const float* ad1  = (const float*)d_in[7];
    const float* b1   = (const float*)d_in[8];
    const float* W2   = (const float*)d_in[9];
    const float* as2  = (const float*)d_in[10];
    const float* ad2  = (const float*)d_in[11];
    const float* b2   = (const float*)d_in[12];
    const float* W3   = (const float*)d_in[13];
    const float* as3  = (const float*)d_in[14];
    const float* ad3  = (const float*)d_in[15];
    const float* b3   = (const float*)d_in[16];
    const float* aggW = (const float*)d_in[17];
    const float* aggb = (const float*)d_in[18];
    const float* muW  = (const float*)d_in[19];
    const float* mub  = (const float*)d_in[20];
    const float* varW = (const float*)d_in[21];
    const float* varb = (const float*)d_in[22];
    float* out = (float*)d_out;

    size_t off = 0;
    auto alloc = [&](size_t bytes) -> char* {
        char* p = (char*)d_ws + off;
        off += (bytes + 255) & ~(size_t)255;
        return p;
    };
    int*   counts  = (int*)alloc((size_t)ZWORDS * 4);   // counts + gbuf contiguous (16B aligned)
    int*   gbuf    = counts + NN;
    u16*   Hbf     = (u16*)alloc((size_t)NPAD * 256 * 2);
    u16*   n0bf    = (u16*)alloc((size_t)NPAD * 64 * 2);
    u16*   nbf     = (u16*)alloc((size_t)NPAD * 256 * 2);
    float* a_s     = (float*)alloc((size_t)NPAD * 4 * 4);
    float* a_d     = (float*)alloc((size_t)NPAD * 4 * 4);
    int*   scanned = (int*)alloc((size_t)NN * 4);
    int*   bsums   = (int*)alloc(256 * 4);
    int*   indptr  = (int*)alloc((size_t)(NN + 1) * 4);
    int*   fill    = (int*)alloc((size_t)NN * 4);
    int*   esrc    = (int*)alloc((size_t)(ETOT + 16) * 4);
    u16*   Wt1     = (u16*)alloc((size_t)256 * 64 * 2);
    u16*   Wt2     = (u16*)alloc((size_t)256 * 256 * 2);
    u16*   Wt3     = (u16*)alloc((size_t)256 * 256 * 2);

    // ZWORDS = 103248, divisible by 4 -> 25812 int4s
    k_zero<<<(ZWORDS / 4 + 255) / 256, 256, 0, stream>>>((int4*)counts);

    k_prep<<<2336, 256, 0, stream>>>(W1, W2, W3, Wt1, Wt2, Wt3,
                                     bf, bf_W, bf_b, batch, n0bf, gbuf,
                                     ei, counts, nbf);

    k_scan_block<<<NB_SCAN, 256, 0, stream>>>(counts, scanned, bsums, NN);
    k_scan_add2<<<NB_SCAN, 256, 0, stream>>>(scanned, bsums, indptr, fill);
    k_fill<<<(ETOT + 255) / 256, 256, 0, stream>>>(ei, indptr, fill, esrc);

    dim3 ggrid(NPAD / BM, 256 / BN);     // (391, 2)
    const int AB = (NN + 31) / 32;       // 1563

    // ---- layer 1 (K=64) ----
    k_gemm_mfma<<<ggrid, 256, 0, stream>>>(n0bf, Wt1, as1, ad1, Hbf, a_s, a_d, 64);
    k_agg<<<AB, 1024, 0, stream>>>(Hbf, a_s, a_d, indptr, esrc, b1, batch, nbf, gbuf, 64);

    // ---- layer 2 (K=256) ----
    k_gemm_mfma<<<ggrid, 256, 0, stream>>>(nbf, Wt2, as2, ad2, Hbf, a_s, a_d, 256);
    k_agg<<<AB, 1024, 0, stream>>>(Hbf, a_s, a_d, indptr, esrc, b2, batch, nbf, gbuf, 320);

    // ---- layer 3 (K=256) ----
    k_gemm_mfma<<<ggrid, 256, 0, stream>>>(nbf, Wt3, as3, ad3, Hbf, a_s, a_d, 256);
    k_agg<<<AB, 1024, 0, stream>>>(Hbf, a_s, a_d, indptr, esrc, b3, batch, nbf, gbuf, 576);

    // ---- head ----
    k_head<<<GG, 1024, 0, stream>>>(gbuf, aggW, aggb, muW, mub, varW, varb, out);
}